// Round 2
// baseline (213.613 us; speedup 1.0000x reference)
//
#include <hip/hip_runtime.h>
#include <hip/hip_bf16.h>
#include <math.h>

#define MDIM 8192
#define NDIM 4096
#define KDIM 128

typedef __bf16 bf16x8 __attribute__((ext_vector_type(8)));
typedef float f32x4 __attribute__((ext_vector_type(4)));

__device__ __forceinline__ unsigned short f32_to_bf16_rne(float f) {
  unsigned int u = __float_as_uint(f);
  u += 0x7fffu + ((u >> 16) & 1u);
  return (unsigned short)(u >> 16);
}

// Convert f32 -> bf16 (vectorized), and compute sum of squares (for ||U||_F, ||V||_F)
__global__ void convert_kernel(const float* __restrict__ X, unsigned short* __restrict__ Xb,
                               double* __restrict__ partial, int n4) {
  int tid = blockIdx.x * blockDim.x + threadIdx.x;
  int stride = gridDim.x * blockDim.x;
  float s = 0.f;
  const float4* X4 = (const float4*)X;
  ushort4* Xb4 = (ushort4*)Xb;
  for (int i = tid; i < n4; i += stride) {
    float4 v = X4[i];
    s += v.x * v.x + v.y * v.y + v.z * v.z + v.w * v.w;
    ushort4 p;
    p.x = f32_to_bf16_rne(v.x);
    p.y = f32_to_bf16_rne(v.y);
    p.z = f32_to_bf16_rne(v.z);
    p.w = f32_to_bf16_rne(v.w);
    Xb4[i] = p;
  }
  for (int off = 32; off > 0; off >>= 1) s += __shfl_down(s, off, 64);
  __shared__ float sw[4];
  int lane = threadIdx.x & 63, wid = threadIdx.x >> 6;
  if (lane == 0) sw[wid] = s;
  __syncthreads();
  if (threadIdx.x == 0) partial[blockIdx.x] = (double)(sw[0] + sw[1] + sw[2] + sw[3]);
}

// Fused P = Xb * Yb^T (K=128, bf16 MFMA) then sum((P - T)^2) over a 128x128 tile.
// 512 threads = 8 waves in a 2x4 grid; each wave owns a 64x32 sub-tile (acc[4][2]).
// T is prefetched as float4 BEFORE the MFMA phase (HBM latency hides under MFMA);
// P goes through a bank-swizzled LDS tile so the compare phase is float4-coalesced.
__global__ __launch_bounds__(512, 4) void fused_tile(
    const unsigned short* __restrict__ Xb,  // [rows][128] bf16 bits
    const unsigned short* __restrict__ Yb,  // [cols][128] bf16 bits
    const float* __restrict__ T,            // [rows][cols]
    double* __restrict__ partial,
    int ldT) {
  __shared__ float P_lds[128][128];
  __shared__ float swred[8];

  const int tid = threadIdx.x;
  const int lane = tid & 63;
  const int wid = tid >> 6;          // 8 waves: 2 (rows) x 4 (cols)
  const int wr = wid >> 2, wc = wid & 3;
  const int l15 = lane & 15;
  const int lg = lane >> 4;          // 0..3

  const int brow = blockIdx.y * 128;
  const int bcol = blockIdx.x * 128;
  const int row0 = brow + wr * 64;   // wave's first row
  const int col0 = bcol + wc * 32;   // wave's first col

  // ---- issue T stream loads early (independent of everything) ----
  const float4* T4 = (const float4*)T;
  const int ldT4 = ldT >> 2;
  float4 t[8];
#pragma unroll
  for (int it = 0; it < 8; ++it) {
    const int f = tid + it * 512;          // 0..4095
    const int r = f >> 5, c4 = f & 31;     // 128 rows x 32 float4-cols
    t[it] = T4[(size_t)(brow + r) * ldT4 + (bcol >> 2) + c4];
  }

  // ---- MFMA phase: P = Xb[rows] * Yb[cols]^T, K=128 ----
  f32x4 acc[4][2] = {};
  const unsigned short* Arow = Xb + (size_t)(row0 + l15) * KDIM + lg * 8;
  const unsigned short* Brow = Yb + (size_t)(col0 + l15) * KDIM + lg * 8;

#pragma unroll
  for (int kk = 0; kk < 4; ++kk) {
    bf16x8 a[4], b[2];
#pragma unroll
    for (int m = 0; m < 4; ++m)
      a[m] = *(const bf16x8*)(Arow + (size_t)m * 16 * KDIM + kk * 32);
#pragma unroll
    for (int n = 0; n < 2; ++n)
      b[n] = *(const bf16x8*)(Brow + (size_t)n * 16 * KDIM + kk * 32);
#pragma unroll
    for (int m = 0; m < 4; ++m)
#pragma unroll
      for (int n = 0; n < 2; ++n)
        acc[m][n] = __builtin_amdgcn_mfma_f32_16x16x32_bf16(a[m], b[n], acc[m][n], 0, 0, 0);
  }

  // ---- store P to LDS, swizzled: col' = col ^ ((row&12)<<2)  (2-way => free) ----
#pragma unroll
  for (int m = 0; m < 4; ++m) {
    const int rl = wr * 64 + m * 16 + lg * 4;
#pragma unroll
    for (int n = 0; n < 2; ++n) {
      const int cl = wc * 32 + n * 16 + l15;
#pragma unroll
      for (int j = 0; j < 4; ++j) {
        const int row = rl + j;
        P_lds[row][cl ^ ((row & 12) << 2)] = acc[m][n][j];
      }
    }
  }
  __syncthreads();

  // ---- compare phase: float4 LDS reads vs prefetched T ----
  float s = 0.f;
#pragma unroll
  for (int it = 0; it < 8; ++it) {
    const int f = tid + it * 512;
    const int r = f >> 5, c4 = f & 31;
    const int c4s = c4 ^ (r & 12);         // matches the write swizzle, float4-granular
    const float4 p = *(const float4*)&P_lds[r][c4s * 4];
    const float dx = p.x - t[it].x;
    const float dy = p.y - t[it].y;
    const float dz = p.z - t[it].z;
    const float dw = p.w - t[it].w;
    s += dx * dx + dy * dy + dz * dz + dw * dw;
  }

  // ---- deterministic block reduction ----
  for (int off = 32; off > 0; off >>= 1) s += __shfl_down(s, off, 64);
  if (lane == 0) swred[wid] = s;
  __syncthreads();
  if (tid == 0) {
    float tot = 0.f;
#pragma unroll
    for (int w = 0; w < 8; ++w) tot += swred[w];
    partial[blockIdx.y * gridDim.x + blockIdx.x] = (double)tot;
  }
}

// Deterministic final reduction of all partial arrays + scalar combine.
__global__ void finalize_kernel(const double* __restrict__ pr, int nr,
                                const double* __restrict__ psm, int nsm,
                                const double* __restrict__ psd, int nsd,
                                const double* __restrict__ pu, int nu,
                                const double* __restrict__ pv, int nv,
                                float* __restrict__ out) {
  __shared__ double sh[256];
  double sums[5];
  const double* ps[5] = {pr, psm, psd, pu, pv};
  int ns[5] = {nr, nsm, nsd, nu, nv};
  for (int q = 0; q < 5; ++q) {
    double s = 0.0;
    for (int i = threadIdx.x; i < ns[q]; i += 256) s += ps[q][i];
    sh[threadIdx.x] = s;
    __syncthreads();
    for (int k = 128; k > 0; k >>= 1) {
      if (threadIdx.x < k) sh[threadIdx.x] += sh[threadIdx.x + k];
      __syncthreads();
    }
    sums[q] = sh[0];
    __syncthreads();
  }
  if (threadIdx.x == 0) {
    double recon = sums[0] / ((double)MDIM * (double)NDIM);
    double res = recon + 0.01 * (sqrt(sums[3]) + sqrt(sums[4]) + sqrt(sums[1]) + sqrt(sums[2]));
    out[0] = (float)res;
  }
}

extern "C" void kernel_launch(void* const* d_in, const int* in_sizes, int n_in,
                              void* d_out, int out_size, void* d_ws, size_t ws_size,
                              hipStream_t stream) {
  const float* A   = (const float*)d_in[0];  // [M][N]
  const float* S_m = (const float*)d_in[1];  // [M][M]
  const float* S_d = (const float*)d_in[2];  // [N][N]
  const float* U   = (const float*)d_in[3];  // [M][K]
  const float* V   = (const float*)d_in[4];  // [N][K]

  char* ws = (char*)d_ws;
  unsigned short* Ub = (unsigned short*)ws;                             // 2 MB
  unsigned short* Vb = (unsigned short*)(ws + (size_t)2 * 1024 * 1024); // 1 MB
  double* pd = (double*)(ws + (size_t)3 * 1024 * 1024);
  double* p_recon = pd;             // 2048 (32x64 grid)
  double* p_sm    = p_recon + 2048; // 4096 (64x64)
  double* p_sd    = p_sm + 4096;    // 1024 (32x32)
  double* p_u     = p_sd + 1024;    // 256
  double* p_v     = p_u + 256;      // 256

  convert_kernel<<<256, 256, 0, stream>>>(U, Ub, p_u, MDIM * KDIM / 4);
  convert_kernel<<<256, 256, 0, stream>>>(V, Vb, p_v, NDIM * KDIM / 4);

  fused_tile<<<dim3(NDIM / 128, MDIM / 128), 512, 0, stream>>>(Ub, Vb, A, p_recon, NDIM);
  fused_tile<<<dim3(MDIM / 128, MDIM / 128), 512, 0, stream>>>(Ub, Ub, S_m, p_sm, MDIM);
  fused_tile<<<dim3(NDIM / 128, NDIM / 128), 512, 0, stream>>>(Vb, Vb, S_d, p_sd, NDIM);

  finalize_kernel<<<1, 256, 0, stream>>>(p_recon, 2048, p_sm, 4096, p_sd, 1024,
                                         p_u, 256, p_v, 256, (float*)d_out);
}

// Round 3
// 201.144 us; speedup vs baseline: 1.0620x; 1.0620x over previous
//
#include <hip/hip_runtime.h>
#include <hip/hip_bf16.h>
#include <math.h>

#define MDIM 8192
#define NDIM 4096
#define KDIM 128

typedef __bf16 bf16x8 __attribute__((ext_vector_type(8)));
typedef float f32x4 __attribute__((ext_vector_type(4)));

__device__ __forceinline__ unsigned short f32_to_bf16_rne(float f) {
  unsigned int u = __float_as_uint(f);
  u += 0x7fffu + ((u >> 16) & 1u);
  return (unsigned short)(u >> 16);
}

// Convert f32 -> bf16 (vectorized), and compute sum of squares (for ||U||_F, ||V||_F)
__global__ void convert_kernel(const float* __restrict__ X, unsigned short* __restrict__ Xb,
                               double* __restrict__ partial, int n4) {
  int tid = blockIdx.x * blockDim.x + threadIdx.x;
  int stride = gridDim.x * blockDim.x;
  float s = 0.f;
  const float4* X4 = (const float4*)X;
  ushort4* Xb4 = (ushort4*)Xb;
  for (int i = tid; i < n4; i += stride) {
    float4 v = X4[i];
    s += v.x * v.x + v.y * v.y + v.z * v.z + v.w * v.w;
    ushort4 p;
    p.x = f32_to_bf16_rne(v.x);
    p.y = f32_to_bf16_rne(v.y);
    p.z = f32_to_bf16_rne(v.z);
    p.w = f32_to_bf16_rne(v.w);
    Xb4[i] = p;
  }
  for (int off = 32; off > 0; off >>= 1) s += __shfl_down(s, off, 64);
  __shared__ float sw[4];
  int lane = threadIdx.x & 63, wid = threadIdx.x >> 6;
  if (lane == 0) sw[wid] = s;
  __syncthreads();
  if (threadIdx.x == 0) partial[blockIdx.x] = (double)(sw[0] + sw[1] + sw[2] + sw[3]);
}

// Fused sum((Xb*Yb^T - T)^2) over one 128x128 tile per block.
// 256 thr = 4 waves (2x2), each wave a 64x64 sub-tile, acc[pcol-tile][prow-tile].
// Operand-swapped MFMA: acc[p][q] = mfma(yfrag[p], xfrag[q]) computes P^T
// fragments, so each lane's f32x4 holds P[row][4 consecutive cols] and the
// T comparison is a single float4 load per MFMA tile (1KB/wave-instr).
// 1D grid with bijective XCD chunking + column-band rasterization: each XCD
// owns one band of W block-cols (W*32KB of Y-panels stay hot in its 4MB L2),
// streaming row-major down the rows.
__global__ __launch_bounds__(256) void fused_tile(
    const unsigned short* __restrict__ Xb,  // [prows][128] bf16 bits
    const unsigned short* __restrict__ Yb,  // [pcols][128] bf16 bits
    const float* __restrict__ T,            // [prows][pcols]
    double* __restrict__ partial,
    int ldT, int Gr, int W) {
  const int tid = threadIdx.x;
  const int lane = tid & 63;
  const int wid = tid >> 6;
  const int wr = wid >> 1, wc = wid & 1;
  const int l15 = lane & 15;
  const int lg = lane >> 4;  // 0..3

  // bijective chunked XCD swizzle (nwg % 8 == 0 always here), then band raster
  const int NB = gridDim.x;
  const int Q = NB >> 3;
  const int g = blockIdx.x;
  const int v = (g & 7) * Q + (g >> 3);
  const int band = v / (W * Gr);
  const int r_blk = (v / W) % Gr;
  const int c_blk = band * W + (v % W);

  const int prow0 = r_blk * 128 + wr * 64;  // wave's first P-row
  const int pcol0 = c_blk * 128 + wc * 64;  // wave's first P-col

  const unsigned short* Xrow = Xb + (size_t)(prow0 + l15) * KDIM + lg * 8;
  const unsigned short* Yrow = Yb + (size_t)(pcol0 + l15) * KDIM + lg * 8;

  f32x4 acc[4][4] = {};  // [p: P-col tile][q: P-row tile]
#pragma unroll
  for (int kk = 0; kk < 4; ++kk) {
    bf16x8 y[4], x[4];
#pragma unroll
    for (int p = 0; p < 4; ++p)
      y[p] = *(const bf16x8*)(Yrow + (size_t)p * 16 * KDIM + kk * 32);
#pragma unroll
    for (int q = 0; q < 4; ++q)
      x[q] = *(const bf16x8*)(Xrow + (size_t)q * 16 * KDIM + kk * 32);
#pragma unroll
    for (int p = 0; p < 4; ++p)
#pragma unroll
      for (int q = 0; q < 4; ++q)
        acc[p][q] = __builtin_amdgcn_mfma_f32_16x16x32_bf16(y[p], x[q], acc[p][q], 0, 0, 0);
  }

  // Epilogue: lane holds P[prow0+q*16+l15][pcol0+p*16+lg*4 .. +3] in acc[p][q]
  const float4* T4 = (const float4*)T;
  const int ldT4 = ldT >> 2;
  float s = 0.f;
#pragma unroll
  for (int q = 0; q < 4; ++q) {
    const size_t rbase = (size_t)(prow0 + q * 16 + l15) * ldT4;
#pragma unroll
    for (int p = 0; p < 4; ++p) {
      const float4 tv = T4[rbase + ((pcol0 + p * 16) >> 2) + lg];
      const f32x4 av = acc[p][q];
      const float dx = av[0] - tv.x;
      const float dy = av[1] - tv.y;
      const float dz = av[2] - tv.z;
      const float dw = av[3] - tv.w;
      s += dx * dx + dy * dy + dz * dz + dw * dw;
    }
  }

  // deterministic block reduction
  for (int off = 32; off > 0; off >>= 1) s += __shfl_down(s, off, 64);
  __shared__ float swred[4];
  if (lane == 0) swred[wid] = s;
  __syncthreads();
  if (tid == 0)
    partial[v] = (double)(swred[0] + swred[1] + swred[2] + swred[3]);
}

// Deterministic final reduction of all partial arrays + scalar combine.
__global__ void finalize_kernel(const double* __restrict__ pr, int nr,
                                const double* __restrict__ psm, int nsm,
                                const double* __restrict__ psd, int nsd,
                                const double* __restrict__ pu, int nu,
                                const double* __restrict__ pv, int nv,
                                float* __restrict__ out) {
  __shared__ double sh[256];
  double sums[5];
  const double* ps[5] = {pr, psm, psd, pu, pv};
  int ns[5] = {nr, nsm, nsd, nu, nv};
  for (int q = 0; q < 5; ++q) {
    double s = 0.0;
    for (int i = threadIdx.x; i < ns[q]; i += 256) s += ps[q][i];
    sh[threadIdx.x] = s;
    __syncthreads();
    for (int k = 128; k > 0; k >>= 1) {
      if (threadIdx.x < k) sh[threadIdx.x] += sh[threadIdx.x + k];
      __syncthreads();
    }
    sums[q] = sh[0];
    __syncthreads();
  }
  if (threadIdx.x == 0) {
    double recon = sums[0] / ((double)MDIM * (double)NDIM);
    double res = recon + 0.01 * (sqrt(sums[3]) + sqrt(sums[4]) + sqrt(sums[1]) + sqrt(sums[2]));
    out[0] = (float)res;
  }
}

extern "C" void kernel_launch(void* const* d_in, const int* in_sizes, int n_in,
                              void* d_out, int out_size, void* d_ws, size_t ws_size,
                              hipStream_t stream) {
  const float* A   = (const float*)d_in[0];  // [M][N]
  const float* S_m = (const float*)d_in[1];  // [M][M]
  const float* S_d = (const float*)d_in[2];  // [N][N]
  const float* U   = (const float*)d_in[3];  // [M][K]
  const float* V   = (const float*)d_in[4];  // [N][K]

  char* ws = (char*)d_ws;
  unsigned short* Ub = (unsigned short*)ws;                             // 2 MB
  unsigned short* Vb = (unsigned short*)(ws + (size_t)2 * 1024 * 1024); // 1 MB
  double* pd = (double*)(ws + (size_t)3 * 1024 * 1024);
  double* p_recon = pd;             // 2048
  double* p_sm    = p_recon + 2048; // 4096
  double* p_sd    = p_sm + 4096;    // 1024
  double* p_u     = p_sd + 1024;    // 256
  double* p_v     = p_u + 256;      // 256

  convert_kernel<<<256, 256, 0, stream>>>(U, Ub, p_u, MDIM * KDIM / 4);
  convert_kernel<<<256, 256, 0, stream>>>(V, Vb, p_v, NDIM * KDIM / 4);

  // recon: P rows = M (Gr=64), cols = N (Gc=32), band W=4  (Q=256=4*64)
  fused_tile<<<2048, 256, 0, stream>>>(Ub, Vb, A, p_recon, NDIM, 64, 4);
  // S_m: Gr=64, Gc=64, W=8  (Q=512=8*64)
  fused_tile<<<4096, 256, 0, stream>>>(Ub, Ub, S_m, p_sm, MDIM, 64, 8);
  // S_d: Gr=32, Gc=32, W=4  (Q=128=4*32)
  fused_tile<<<1024, 256, 0, stream>>>(Vb, Vb, S_d, p_sd, NDIM, 32, 4);

  finalize_kernel<<<1, 256, 0, stream>>>(p_recon, 2048, p_sm, 4096, p_sd, 1024,
                                         p_u, 256, p_v, 256, (float*)d_out);
}